// Round 9
// baseline (258.339 us; speedup 1.0000x reference)
//
#include <hip/hip_runtime.h>
#include <math.h>

// TrueMambaS6Block v9. B=16, L=4096, D=64, N=16.
// Fused structure (delta/B~/C never touch global), retuned for occupancy and
// LDS-pipe pressure: TPB=64 (4 blocks/CU co-resident), conflict-free-ish LDS
// strides, and a per-thread-row GEMV (16 ds_read_b128/wave instead of 512
// broadcast reads) with an in-place LDS transpose for coalesced stores.
//
//  k1 scan_fused1: block=64 tokens (1024 blocks): proj(delta,B~)->LDS,
//                  wave=16-token chunk local scan (h0=0), fp16 (P,S) out.
//  k2 scan_phase2: per (b,n,d): combine 256 chunks; carry in place in Ach.
//  k3 scan_fused3: proj(delta,B~,C)->LDS, re-scan from carry, y->LDS(fp32),
//                  GEMV: thread=token reads own y row, W via s_load,
//                  transpose through sDel, coalesced out.
//
// ws: Ach 8MB (fp16) | Sch 8MB (fp16)

#define BB 16
#define LL 4096
#define DD 64
#define NN 16
#define TPB 64             // tokens per block
#define CH 16              // chunk length (1 wave per chunk)
#define NCHB (LL/CH)       // 256 chunks per batch
#define LOG2E 1.44269504f

typedef _Float16 h16;

// LDS strides:
//  sDel: 68 floats/row (272B: 16B-aligned rows for b128; scan reads stride-1
//        free; proj writes 8-way once per e; doubles as y rows then as the
//        out-transpose buffer).
//  sXp : 33 dwords/row of packed fp16 pairs (bank stride 1: conflict-free).
//  sB/sC: 20 floats/row (80B aligned; writes 8-way; scan row reads = 4
//        broadcast b128, conflict-free).

// ---------------------------------------------------------------- k1
__global__ __launch_bounds__(256, 4) void scan_fused1(
    const float* __restrict__ x, const float* __restrict__ A_log,
    const float* __restrict__ Wd, const float* __restrict__ Wdb,
    const float* __restrict__ WB,
    h16* __restrict__ Ach, h16* __restrict__ Sch)
{
    __shared__ float sDel[TPB * 68];          // 17.4 KB
    __shared__ unsigned int sXp[TPB * 33];    //  8.25 KB
    __shared__ float sB[TPB * 20];            //  5.1 KB  -> ~30.8 KB
    const int tid = threadIdx.x;
    const int w = __builtin_amdgcn_readfirstlane(tid >> 6);
    const int l = tid & 63;
    const int b = blockIdx.x >> 6;
    const int grp = blockIdx.x & 63;
    const int tok0 = b * LL + grp * TPB;

    // ---- x row of token l (all 4 waves redundantly: L2-hit)
    float xv[DD];
    {
        const float4* xr = (const float4*)(x + (size_t)(tok0 + l) * DD);
#pragma unroll
        for (int i = 0; i < 16; ++i) {
            float4 v = xr[i];
            xv[4*i] = v.x; xv[4*i+1] = v.y; xv[4*i+2] = v.z; xv[4*i+3] = v.w;
        }
    }
    if (w == 0) {   // stage x as packed fp16 pairs for the scan
#pragma unroll
        for (int j = 0; j < 32; ++j) {
            h16 lo = (h16)xv[2*j], hi = (h16)xv[2*j+1];
            unsigned int p;
            union { h16 h[2]; unsigned int u; } cvt;
            cvt.h[0] = lo; cvt.h[1] = hi; p = cvt.u;
            sXp[l * 33 + j] = p;
        }
    }
    // ---- proj delta: wave w -> e in [16w, 16w+16)
#pragma unroll 2
    for (int j = 0; j < 16; ++j) {
        const int e = w * 16 + j;
        const float* wr = Wd + (size_t)e * DD;     // wave-uniform -> s_load
        float a0 = Wdb[e], a1 = 0.f, a2 = 0.f, a3 = 0.f;
#pragma unroll
        for (int k = 0; k < DD; k += 4) {
            a0 = fmaf(xv[k+0], wr[k+0], a0);
            a1 = fmaf(xv[k+1], wr[k+1], a1);
            a2 = fmaf(xv[k+2], wr[k+2], a2);
            a3 = fmaf(xv[k+3], wr[k+3], a3);
        }
        const float z = (a0 + a1) + (a2 + a3);
        const float t2 = __expf(-fabsf(z));
        sDel[l * 68 + e] = fmaxf(z, 0.f) + __logf(1.f + t2);
    }
    // ---- proj B~: wave w -> n in [4w, 4w+4); fold 1/A_real
#pragma unroll
    for (int j = 0; j < 4; ++j) {
        const int n = w * 4 + j;
        const float* wr = WB + (size_t)n * DD;
        float a0 = 0.f, a1 = 0.f, a2 = 0.f, a3 = 0.f;
#pragma unroll
        for (int k = 0; k < DD; k += 4) {
            a0 = fmaf(xv[k+0], wr[k+0], a0);
            a1 = fmaf(xv[k+1], wr[k+1], a1);
            a2 = fmaf(xv[k+2], wr[k+2], a2);
            a3 = fmaf(xv[k+3], wr[k+3], a3);
        }
        sB[l * 20 + n] = ((a0 + a1) + (a2 + a3)) * (-__expf(-A_log[n]));
    }
    float A2[NN];
    {
        const float4* ap = (const float4*)(A_log + l * NN);
#pragma unroll
        for (int i = 0; i < 4; ++i) {
            float4 v = ap[i];
            A2[4*i+0] = -__expf(v.x) * LOG2E;
            A2[4*i+1] = -__expf(v.y) * LOG2E;
            A2[4*i+2] = -__expf(v.z) * LOG2E;
            A2[4*i+3] = -__expf(v.w) * LOG2E;
        }
    }
    __syncthreads();

    // ---- local scan: wave w scans tokens [16w, 16w+16), h0 = 0
    float h[NN];
#pragma unroll
    for (int n = 0; n < NN; ++n) h[n] = 0.f;
    float sd = 0.f;
    const int bt0 = w * CH;
#pragma unroll 4
    for (int s = 0; s < CH; ++s) {
        const int t = bt0 + s;
        const float dl = sDel[t * 68 + l];
        const float xvv = (float)((const h16*)sXp)[t * 66 + l];
        sd += dl;
        const float4* b4 = (const float4*)(sB + t * 20);
        float bt[NN];
#pragma unroll
        for (int i = 0; i < 4; ++i) {
            float4 v = b4[i];                       // broadcast
            bt[4*i] = v.x; bt[4*i+1] = v.y; bt[4*i+2] = v.z; bt[4*i+3] = v.w;
        }
#pragma unroll
        for (int n = 0; n < NN; ++n) {
            const float a = __builtin_amdgcn_exp2f(dl * A2[n]);
            const float wv = bt[n] * xvv;
            h[n] = fmaf(a, h[n] + wv, -wv);
        }
    }
    const int g = blockIdx.x * 4 + w;               // global chunk id
#pragma unroll
    for (int n = 0; n < NN; ++n) {
        const size_t o = ((size_t)g * NN + n) * DD + l;   // [g][n][d]
        Ach[o] = (h16)__builtin_amdgcn_exp2f(A2[n] * sd);
        Sch[o] = (h16)h[n];
    }
}

// ---------------------------------------------------------------- k2
// Thread = (b, n*64+d): combine 256 chunks, 16-wide prefetch; carry written
// in place into Ach (each slot read before overwrite by the same thread).
__global__ __launch_bounds__(64) void scan_phase2(
    h16* __restrict__ Ach, const h16* __restrict__ Sch)
{
    const int gid = blockIdx.x * 64 + threadIdx.x;  // [0, B*D*N)
    const int b = gid >> 10, r = gid & 1023;
    const size_t base = (size_t)b * NCHB * 1024 + r;
    float H = 0.f;
    for (int cg = 0; cg < NCHB; cg += 16) {
        float a[16], s[16];
#pragma unroll
        for (int i = 0; i < 16; ++i) {
            const size_t o = base + (size_t)(cg + i) * 1024;
            a[i] = (float)Ach[o];
            s[i] = (float)Sch[o];
        }
#pragma unroll
        for (int i = 0; i < 16; ++i) {
            const size_t o = base + (size_t)(cg + i) * 1024;
            Ach[o] = (h16)H;                 // carry entering chunk cg+i
            H = fmaf(a[i], H, s[i]);
        }
    }
}

// ---------------------------------------------------------------- k3
__global__ __launch_bounds__(256, 4) void scan_fused3(
    const float* __restrict__ x, const float* __restrict__ A_log,
    const float* __restrict__ Wd, const float* __restrict__ Wdb,
    const float* __restrict__ WB, const float* __restrict__ WC,
    const float* __restrict__ Dskip,
    const float* __restrict__ Wout, const float* __restrict__ Woutb,
    const h16* __restrict__ carry, float* __restrict__ out)
{
    __shared__ float sDel[TPB * 68];          // delta -> y rows -> out-transpose
    __shared__ unsigned int sXp[TPB * 33];
    __shared__ float sB[TPB * 20];
    __shared__ float sC[TPB * 20];            // ~36 KB -> 4 blocks/CU
    const int tid = threadIdx.x;
    const int w = __builtin_amdgcn_readfirstlane(tid >> 6);
    const int l = tid & 63;
    const int b = blockIdx.x >> 6;
    const int grp = blockIdx.x & 63;
    const int tok0 = b * LL + grp * TPB;

    float xv[DD];
    {
        const float4* xr = (const float4*)(x + (size_t)(tok0 + l) * DD);
#pragma unroll
        for (int i = 0; i < 16; ++i) {
            float4 v = xr[i];
            xv[4*i] = v.x; xv[4*i+1] = v.y; xv[4*i+2] = v.z; xv[4*i+3] = v.w;
        }
    }
    if (w == 0) {
#pragma unroll
        for (int j = 0; j < 32; ++j) {
            union { h16 h[2]; unsigned int u; } cvt;
            cvt.h[0] = (h16)xv[2*j]; cvt.h[1] = (h16)xv[2*j+1];
            sXp[l * 33 + j] = cvt.u;
        }
    }
#pragma unroll 2
    for (int j = 0; j < 16; ++j) {
        const int e = w * 16 + j;
        const float* wr = Wd + (size_t)e * DD;
        float a0 = Wdb[e], a1 = 0.f, a2 = 0.f, a3 = 0.f;
#pragma unroll
        for (int k = 0; k < DD; k += 4) {
            a0 = fmaf(xv[k+0], wr[k+0], a0);
            a1 = fmaf(xv[k+1], wr[k+1], a1);
            a2 = fmaf(xv[k+2], wr[k+2], a2);
            a3 = fmaf(xv[k+3], wr[k+3], a3);
        }
        const float z = (a0 + a1) + (a2 + a3);
        const float t2 = __expf(-fabsf(z));
        sDel[l * 68 + e] = fmaxf(z, 0.f) + __logf(1.f + t2);
    }
    {   // B~/C: wave 0: B n0-7, wave 1: B n8-15, wave 2: C n0-7, wave 3: C n8-15
        const int isC = w >> 1;
        const int nb = (w & 1) * 8;
        const float* __restrict__ Wbc = isC ? WC : WB;
        float* __restrict__ dst = isC ? sC : sB;
#pragma unroll
        for (int j = 0; j < 8; ++j) {
            const int n = nb + j;
            const float* wr = Wbc + (size_t)n * DD;
            float a0 = 0.f, a1 = 0.f, a2 = 0.f, a3 = 0.f;
#pragma unroll
            for (int k = 0; k < DD; k += 4) {
                a0 = fmaf(xv[k+0], wr[k+0], a0);
                a1 = fmaf(xv[k+1], wr[k+1], a1);
                a2 = fmaf(xv[k+2], wr[k+2], a2);
                a3 = fmaf(xv[k+3], wr[k+3], a3);
            }
            float acc = (a0 + a1) + (a2 + a3);
            if (!isC) acc *= -__expf(-A_log[n]);
            dst[l * 20 + n] = acc;
        }
    }
    float A2[NN];
    {
        const float4* ap = (const float4*)(A_log + l * NN);
#pragma unroll
        for (int i = 0; i < 4; ++i) {
            float4 v = ap[i];
            A2[4*i+0] = -__expf(v.x) * LOG2E;
            A2[4*i+1] = -__expf(v.y) * LOG2E;
            A2[4*i+2] = -__expf(v.z) * LOG2E;
            A2[4*i+3] = -__expf(v.w) * LOG2E;
        }
    }
    const float Dsk = Dskip[l];
    const int g = blockIdx.x * 4 + w;
    float h[NN];
#pragma unroll
    for (int n = 0; n < NN; ++n) h[n] = (float)carry[((size_t)g * NN + n) * DD + l];
    __syncthreads();

    // ---- re-scan from carry; y overwrites delta row t (dead after step t)
    const int bt0 = w * CH;
#pragma unroll 4
    for (int s = 0; s < CH; ++s) {
        const int t = bt0 + s;
        const float dl = sDel[t * 68 + l];
        const float xvv = (float)((const h16*)sXp)[t * 66 + l];
        float bt[NN], cn[NN];
        {
            const float4* b4 = (const float4*)(sB + t * 20);
            const float4* c4 = (const float4*)(sC + t * 20);
#pragma unroll
            for (int i = 0; i < 4; ++i) {
                float4 v = b4[i];
                bt[4*i] = v.x; bt[4*i+1] = v.y; bt[4*i+2] = v.z; bt[4*i+3] = v.w;
                float4 u = c4[i];
                cn[4*i] = u.x; cn[4*i+1] = u.y; cn[4*i+2] = u.z; cn[4*i+3] = u.w;
            }
        }
        float p0 = 0.f, p1 = 0.f, p2 = 0.f, p3 = 0.f;
#pragma unroll
        for (int n = 0; n < NN; ++n) {
            const float a = __builtin_amdgcn_exp2f(dl * A2[n]);
            const float wv = bt[n] * xvv;
            h[n] = fmaf(a, h[n] + wv, -wv);
            const float hv = h[n];
            if ((n & 3) == 0)      p0 = fmaf(cn[n], hv, p0);
            else if ((n & 3) == 1) p1 = fmaf(cn[n], hv, p1);
            else if ((n & 3) == 2) p2 = fmaf(cn[n], hv, p2);
            else                   p3 = fmaf(cn[n], hv, p3);
        }
        sDel[t * 68 + l] = fmaf(Dsk, xvv, (p0 + p1) + (p2 + p3));
    }
    __syncthreads();

    // ---- GEMV: thread = token l, e-range [16w, 16w+16). Read own y row
    // (per-lane b128: 16 instr/wave), weights via s_load.
    float yv[DD];
    {
        const float4* yr = (const float4*)(sDel + l * 68);
#pragma unroll
        for (int i = 0; i < 16; ++i) {
            float4 v = yr[i];
            yv[4*i] = v.x; yv[4*i+1] = v.y; yv[4*i+2] = v.z; yv[4*i+3] = v.w;
        }
    }
    __syncthreads();   // everyone done reading y before sDel is overwritten
    float ov[16];
#pragma unroll 2
    for (int j = 0; j < 16; ++j) {
        const int e = w * 16 + j;
        const float* wr = Wout + (size_t)e * DD;    // wave-uniform -> s_load
        float a0 = Woutb[e], a1 = 0.f, a2 = 0.f, a3 = 0.f;
#pragma unroll
        for (int k = 0; k < DD; k += 4) {
            a0 = fmaf(yv[k+0], wr[k+0], a0);
            a1 = fmaf(yv[k+1], wr[k+1], a1);
            a2 = fmaf(yv[k+2], wr[k+2], a2);
            a3 = fmaf(yv[k+3], wr[k+3], a3);
        }
        ov[j] = (a0 + a1) + (a2 + a3);
    }
#pragma unroll
    for (int j = 0; j < 16; ++j) sDel[l * 68 + w * 16 + j] = ov[j];
    __syncthreads();

    // ---- coalesced store: thread (w,l) writes tokens [16w,16w+16), column l
#pragma unroll 4
    for (int s = 0; s < CH; ++s) {
        const int t = bt0 + s;
        out[(size_t)(tok0 + t) * DD + l] = sDel[t * 68 + l];
    }
}

// ---------------------------------------------------------------- launch
extern "C" void kernel_launch(void* const* d_in, const int* in_sizes, int n_in,
                              void* d_out, int out_size, void* d_ws, size_t ws_size,
                              hipStream_t stream) {
    (void)in_sizes; (void)n_in; (void)out_size; (void)ws_size;
    const float* x     = (const float*)d_in[0];
    const float* A_log = (const float*)d_in[1];
    const float* Dskip = (const float*)d_in[2];
    const float* Wout  = (const float*)d_in[3];
    const float* Woutb = (const float*)d_in[4];
    const float* Wd    = (const float*)d_in[5];
    const float* Wdb   = (const float*)d_in[6];
    const float* WB    = (const float*)d_in[7];
    const float* WC    = (const float*)d_in[8];
    float* out = (float*)d_out;

    h16* Ach = (h16*)d_ws;                               // [4096][16][64] fp16
    h16* Sch = Ach + (size_t)BB * NCHB * NN * DD;        // [4096][16][64] fp16

    scan_fused1<<<BB * 64, 256, 0, stream>>>(x, A_log, Wd, Wdb, WB, Ach, Sch);
    scan_phase2<<<BB * DD * NN / 64, 64, 0, stream>>>(Ach, Sch);
    scan_fused3<<<BB * 64, 256, 0, stream>>>(x, A_log, Wd, Wdb, WB, WC, Dskip,
                                             Wout, Woutb, Ach, out);
}